// Round 9
// baseline (121.922 us; speedup 1.0000x reference)
//
#include <hip/hip_runtime.h>

// out = irfft2( rfft2(x_grid) * W ), ortho, grid 16x16, C=768, B=256.
// R2 structure (fp32 LDS E, 33KB, conflict-free) + register-resident
// cross-tile prefetch: block = (ct, batch-pair), BOTH tiles' x loaded into
// VGPRs up front, so b1's HBM latency hides under b0's S1-S3 compute.
// Barriers are s_barrier + lgkmcnt(0) only (stores/prefetch stay in flight).
// Reg budget: launch_bounds(256,4) -> 128; peak live ~ 32 (z1) + 32 (fft
// state) + ~25 (interleaved weights + addrs) < 128 -> no spill (R4/R6
// lesson: any tighter waves-cap spills ~60-reg FFT state to scratch).

#define DIM 768
#define CT 32
#define NCT (DIM / CT)   // 24
#define IP 258           // float2 pitch per i-row: 8 slots * 32 ch + 2 pad

#define R2c  0.70710678118654752f
#define C1c  0.92387953251128674f
#define S1cc 0.38268343236508978f
#define INV512  (1.f / 512.f)
#define INV256  (1.f / 256.f)
#define INV1024 (1.f / 1024.f)

#define BARL() { asm volatile("s_waitcnt lgkmcnt(0)" ::: "memory"); __builtin_amdgcn_s_barrier(); }

template <int SGN>   // SGN = -1 forward, +1 inverse (unnormalized)
__device__ __forceinline__ void fft16(float* xr, float* xi) {
#define SWP(a, b) { float t_ = xr[a]; xr[a] = xr[b]; xr[b] = t_; t_ = xi[a]; xi[a] = xi[b]; xi[b] = t_; }
  SWP(1, 8) SWP(2, 4) SWP(3, 12) SWP(5, 10) SWP(7, 14) SWP(11, 13)
#undef SWP
#define BF1(a, b) { float tr = xr[b], ti = xi[b]; xr[b] = xr[a] - tr; xi[b] = xi[a] - ti; xr[a] += tr; xi[a] += ti; }
#define BFI(a, b) { float tr, ti; if (SGN < 0) { tr = xi[b]; ti = -xr[b]; } else { tr = -xi[b]; ti = xr[b]; } \
                    xr[b] = xr[a] - tr; xi[b] = xi[a] - ti; xr[a] += tr; xi[a] += ti; }
#define BFW(a, b, Wr, Wi) { float tr = (Wr) * xr[b] - (Wi) * xi[b], ti = (Wr) * xi[b] + (Wi) * xr[b]; \
                            xr[b] = xr[a] - tr; xi[b] = xi[a] - ti; xr[a] += tr; xi[a] += ti; }
  BF1(0, 1) BF1(2, 3) BF1(4, 5) BF1(6, 7) BF1(8, 9) BF1(10, 11) BF1(12, 13) BF1(14, 15)
  BF1(0, 2) BF1(4, 6) BF1(8, 10) BF1(12, 14)
  BFI(1, 3) BFI(5, 7) BFI(9, 11) BFI(13, 15)
  BF1(0, 4) BF1(8, 12)
  BFW(1, 5, R2c, SGN * R2c) BFW(9, 13, R2c, SGN * R2c)
  BFI(2, 6) BFI(10, 14)
  BFW(3, 7, -R2c, SGN * R2c) BFW(11, 15, -R2c, SGN * R2c)
  BF1(0, 8)
  BFW(1, 9, C1c, SGN * S1cc)
  BFW(2, 10, R2c, SGN * R2c)
  BFW(3, 11, S1cc, SGN * C1c)
  BFI(4, 12)
  BFW(5, 13, -S1cc, SGN * C1c)
  BFW(6, 14, -R2c, SGN * R2c)
  BFW(7, 15, -C1c, SGN * S1cc)
#undef BF1
#undef BFI
#undef BFW
}

__global__ __launch_bounds__(256, 4) void gf9_kernel(const float* __restrict__ x,
                                                     const float* __restrict__ w,
                                                     float* __restrict__ out) {
  __shared__ __align__(16) float2 E[16 * IP];   // 33 KB, U then aliased as Q
  float4* E4 = (float4*)E;

  const int blk = blockIdx.x;
  const int ct = blk >> 7;        // 0..23  (ct-outer: W slice L2-hot)
  const int bp = blk & 127;       // batch pair
  const int b0 = bp * 2;
  const int c0 = ct * CT;
  const int t  = threadIdx.x;
  const int r  = t >> 4;          // i (S1) / n1 (S3)
  const int p  = t & 15;          // channel-pair index
  const int s  = t >> 5;          // S2: slot 0..7
  const int c  = t & 31;          // S2: channel within tile

  // ---- issue BOTH tiles' x loads up front (b1's latency hides under b0) ----
  float zr0[16], zi0[16], zr1[16], zi1[16];
  {
    const float2* xp = (const float2*)(x + (size_t)b0 * 196608 + (size_t)r * 12288 + c0) + p;
#pragma unroll
    for (int j = 0; j < 16; j++) { float2 v = xp[j * 384]; zr0[j] = v.x; zi0[j] = v.y; }
    const float2* xq = xp + 98304;   // batch b0+1
#pragma unroll
    for (int j = 0; j < 16; j++) { float2 v = xq[j * 384]; zr1[j] = v.x; zi1[j] = v.y; }
  }

#define TILE_BODY(ZR, ZI, BB)                                                  \
  {                                                                            \
    /* S1: rfft over j, 2 channels packed (data already in regs) */           \
    fft16<-1>(ZR, ZI);                                                         \
    {                                                                          \
      E4[r * 129 + p] = make_float4(ZR[0], ZR[8], ZI[0], ZI[8]);               \
    }                                                                          \
    _Pragma("unroll")                                                          \
    for (int k = 1; k <= 7; k++) {                                             \
      const int m = 16 - k;                                                    \
      float Ar = ZR[k] + ZR[m], Ai = ZI[k] - ZI[m];                            \
      float Br = ZI[k] + ZI[m], Bi = ZR[m] - ZR[k];                            \
      E4[r * 129 + k * 16 + p] = make_float4(Ar, Ai, Br, Bi);                  \
    }                                                                          \
    BARL();                                                                    \
    /* S2: fft over i, weight, ifft over k1 */                                 \
    {                                                                          \
      float gr[16], gi[16];                                                    \
      const float2* col = E + s * 32 + c;                                      \
      _Pragma("unroll")                                                        \
      for (int i = 0; i < 16; i++) { float2 v = col[i * IP]; gr[i] = v.x; gi[i] = v.y; } \
      BARL();                       /* all E reads done before overwrite */    \
      fft16<-1>(gr, gi);                                                       \
      if (s == 0) {                                                            \
        const float* wc = w + (size_t)(c0 + c) * 2;                            \
        {                                                                      \
          float2 a0 = *(const float2*)(wc);                                    \
          float2 a8 = *(const float2*)(wc + 12288);                            \
          float2 b0_ = *(const float2*)(wc + 8 * 13824);                       \
          float2 b8 = *(const float2*)(wc + 8 * 13824 + 12288);                \
          gr[0] = gr[0] * (a0.x * INV256);                                     \
          gi[0] = gi[0] * (a8.x * INV256);                                     \
          gr[8] = gr[8] * (b0_.x * INV256);                                    \
          gi[8] = gi[8] * (b8.x * INV256);                                     \
        }                                                                      \
        _Pragma("unroll")                                                      \
        for (int k = 1; k <= 7; k++) {                                         \
          const int m = 16 - k;                                                \
          float2 a0 = *(const float2*)(wc + (size_t)k * 13824);                \
          float2 m0 = *(const float2*)(wc + (size_t)m * 13824);                \
          float2 a8 = *(const float2*)(wc + (size_t)k * 13824 + 12288);        \
          float2 m8 = *(const float2*)(wc + (size_t)m * 13824 + 12288);        \
          float Vpr = (a0.x + m0.x + a8.x + m8.x) * INV1024;                   \
          float Vpi = (a0.y - m0.y + a8.y - m8.y) * INV1024;                   \
          float Vmr = (a0.x + m0.x - a8.x - m8.x) * INV1024;                   \
          float Vmi = (a0.y - m0.y - a8.y + m8.y) * INV1024;                   \
          float ur = gr[k], ui = gi[k], vr = gr[m], vi = gi[m];                \
          float nkr = ur * Vpr - ui * Vpi + vr * Vmr + vi * Vmi;               \
          float nki = ur * Vpi + ui * Vpr + vr * Vmi - vi * Vmr;               \
          float nmr = vr * Vpr + vi * Vpi + ur * Vmr - ui * Vmi;               \
          float nmi = vi * Vpr - vr * Vpi - ur * Vmi - ui * Vmr;               \
          gr[k] = nkr; gi[k] = nki; gr[m] = nmr; gi[m] = nmi;                  \
        }                                                                      \
      } else {                                                                 \
        const float* wp = w + (size_t)(s * 768 + c0 + c) * 2;                  \
        _Pragma("unroll")                                                      \
        for (int k1 = 0; k1 < 16; k1++) {                                      \
          float2 wv = *(const float2*)(wp + (size_t)k1 * 13824);               \
          const float wr_ = wv.x * INV512, wi_ = wv.y * INV512;                \
          float yr = gr[k1] * wr_ - gi[k1] * wi_;                              \
          float yi = gr[k1] * wi_ + gi[k1] * wr_;                              \
          gr[k1] = yr; gi[k1] = yi;                                            \
        }                                                                      \
      }                                                                        \
      fft16<1>(gr, gi);                                                        \
      float2* colo = E + s * 32 + c;                                           \
      _Pragma("unroll")                                                        \
      for (int n1 = 0; n1 < 16; n1++) { colo[n1 * IP] = make_float2(gr[n1], gi[n1]); } \
    }                                                                          \
    BARL();                                                                    \
    /* S3: irfft over k2, 2 channels packed, store */                          \
    {                                                                          \
      float hr[16], hq[16];                                                    \
      _Pragma("unroll")                                                        \
      for (int k = 0; k <= 7; k++) {                                           \
        float4 v = E4[r * 129 + k * 16 + p];                                   \
        if (k == 0) {                                                          \
          hr[0] = v.x; hq[0] = v.z;                                            \
          hr[8] = v.y; hq[8] = v.w;                                            \
        } else {                                                               \
          hr[k] = v.x - v.w;      hq[k] = v.y + v.z;                           \
          hr[16 - k] = v.x + v.w; hq[16 - k] = v.z - v.y;                      \
        }                                                                      \
      }                                                                        \
      fft16<1>(hr, hq);                                                        \
      float2* op = (float2*)(out + (size_t)(BB) * 196608 + (size_t)r * 12288 + c0) + p; \
      _Pragma("unroll")                                                        \
      for (int n2 = 0; n2 < 16; n2++) { op[n2 * 384] = make_float2(hr[n2], hq[n2]); } \
    }                                                                          \
  }

  TILE_BODY(zr0, zi0, b0)
  BARL();   // S3 E-reads done before next tile's S1 E-writes (no vmcnt drain)
  TILE_BODY(zr1, zi1, b0 + 1)

#undef TILE_BODY
}

extern "C" void kernel_launch(void* const* d_in, const int* in_sizes, int n_in,
                              void* d_out, int out_size, void* d_ws, size_t ws_size,
                              hipStream_t stream) {
  const float* x = (const float*)d_in[0];
  const float* w = (const float*)d_in[1];
  float* out = (float*)d_out;
  dim3 grid(NCT * 128);   // 24 ct x 128 batch-pairs = 3072
  dim3 block(256);
  hipLaunchKernelGGL(gf9_kernel, grid, block, 0, stream, x, w, out);
}